// Round 5
// baseline (675.639 us; speedup 1.0000x reference)
//
#include <hip/hip_runtime.h>
#include <hip/hip_bf16.h>

#define NN 8192
#define MM 16384
#define EE 131072
#define K2 32768

typedef unsigned short u16;
typedef unsigned int u32;
typedef __attribute__((ext_vector_type(8))) short bf16x8;
typedef __attribute__((ext_vector_type(4))) float f32x4;
typedef __attribute__((ext_vector_type(4))) float f4;

__device__ __forceinline__ u16 f2bf(float f){
  union { float f; unsigned u; } x; x.f = f;
  return (u16)((x.u + 0x7FFFu + ((x.u >> 16) & 1u)) >> 16);   // RNE
}

__device__ __forceinline__ bf16x8 cvt8(f4 a, f4 b){            // RNE path (prep kernels)
  bf16x8 r;
  r[0]=(short)f2bf(a.x); r[1]=(short)f2bf(a.y);
  r[2]=(short)f2bf(a.z); r[3]=(short)f2bf(a.w);
  r[4]=(short)f2bf(b.x); r[5]=(short)f2bf(b.y);
  r[6]=(short)f2bf(b.z); r[7]=(short)f2bf(b.w);
  return r;
}

// truncating pack: one v_perm_b32 per 2 floats (hot path: fuse_gemm A-convert)
__device__ __forceinline__ bf16x8 cvt8t(f4 a, f4 b){
  union { u32 u[4]; bf16x8 v; } r;
  r.u[0] = __builtin_amdgcn_perm(__float_as_uint(a.y), __float_as_uint(a.x), 0x07060302u);
  r.u[1] = __builtin_amdgcn_perm(__float_as_uint(a.w), __float_as_uint(a.z), 0x07060302u);
  r.u[2] = __builtin_amdgcn_perm(__float_as_uint(b.y), __float_as_uint(b.x), 0x07060302u);
  r.u[3] = __builtin_amdgcn_perm(__float_as_uint(b.w), __float_as_uint(b.z), 0x07060302u);
  return r.v;
}

// WfT[co][j] = bf16(W_fuse[(co>>7)*128 + j][co&127])
__global__ void wft_k(const float* __restrict__ W_fuse, u16* __restrict__ WfT){
  int co = blockIdx.x, j = threadIdx.x;
  int c = co >> 7, o = co & 127;
  WfT[co*128 + j] = f2bf(W_fuse[(c*128 + j)*128 + o]);
}

// B' = interleaved [feat_b @ Wf_top ; feat_b @ Wf_bot] in fragment-ordered layout:
// Bpack byte addr = k32tile*8192 + o*64 + chunk*16, chunk = (k&31)>>3, k = 2m+c.
// Per-wave stores are contiguous 1KB per cf (coalesced).
__global__ __launch_bounds__(128) void prep_bpt(const float* __restrict__ feat_b,
                                                const u16* __restrict__ WfT,
                                                char* __restrict__ Bpack){
  int t = threadIdx.x, w = t >> 6, l = t & 63;
  int lr = l & 15, lk = l >> 4;
  int mrow = blockIdx.x*32 + w*16;               // 512 blocks x 2 waves; wave = 16 m-rows = one k32 tile
  f32x4 acc[16] = {};
  const float* ap = feat_b + (size_t)(mrow + lr)*128 + lk*8;
  #pragma unroll
  for (int ks = 0; ks < 4; ++ks){
    f4 a0 = *(const f4*)(ap + ks*32);
    f4 a1 = *(const f4*)(ap + ks*32 + 4);
    bf16x8 a = cvt8(a0, a1);
    #pragma unroll
    for (int cf = 0; cf < 16; ++cf){
      bf16x8 b = *(const bf16x8*)(WfT + (cf*16 + lr)*128 + ks*32 + lk*8);
      acc[cf] = __builtin_amdgcn_mfma_f32_16x16x32_bf16(a, b, acc[cf], 0, 0, 0);
    }
  }
  // acc[cf][j] is C[m=mrow+lk*4+j][o=cf*16+lr] (c=0); acc[cf+8][j] same for c=1.
  // k = 2m+c -> uint4 covers 8 consecutive k starting at 2*(mrow+lk*4) -> chunk index = lk.
  char* dstb = Bpack + (size_t)(mrow >> 4)*8192 + lk*16;
  #pragma unroll
  for (int cf = 0; cf < 8; ++cf){
    int o = cf*16 + lr;
    uint4 v;
    v.x = (u32)f2bf(acc[cf][0]) | ((u32)f2bf(acc[cf+8][0]) << 16);
    v.y = (u32)f2bf(acc[cf][1]) | ((u32)f2bf(acc[cf+8][1]) << 16);
    v.z = (u32)f2bf(acc[cf][2]) | ((u32)f2bf(acc[cf+8][2]) << 16);
    v.w = (u32)f2bf(acc[cf][3]) | ((u32)f2bf(acc[cf+8][3]) << 16);
    *(uint4*)(dstb + o*64) = v;
  }
}

// CSR build
__global__ void hist_k(const int* __restrict__ dst, int* __restrict__ hist){
  int e = blockIdx.x*256 + threadIdx.x;
  atomicAdd(hist + dst[e], 1);
}

__global__ void scan_k(const int* __restrict__ hist, int* __restrict__ off,
                       int* __restrict__ cursor){
  __shared__ int part[256];
  int t = threadIdx.x;
  int loc[32]; int s = 0;
  #pragma unroll
  for (int i = 0; i < 32; ++i){ loc[i] = hist[t*32 + i]; s += loc[i]; }
  part[t] = s;
  __syncthreads();
  for (int d = 1; d < 256; d <<= 1){
    int v = (t >= d) ? part[t-d] : 0;
    __syncthreads();
    part[t] += v;
    __syncthreads();
  }
  int run = (t > 0) ? part[t-1] : 0;
  #pragma unroll
  for (int i = 0; i < 32; ++i){ off[t*32+i] = run; cursor[t*32+i] = run; run += loc[i]; }
  if (t == 255) off[NN] = run;
}

__global__ void fill_k(const int* __restrict__ src, const int* __restrict__ dst,
                       int* __restrict__ cursor, int* __restrict__ eidx){
  int e = blockIdx.x*256 + threadIdx.x;
  int pos = atomicAdd(cursor + dst[e], 1);
  eidx[pos] = src[e];
}

// agg: zout[n] = sum_{e: dst[e]=n} zin[src[e]]
__global__ __launch_bounds__(256) void agg_k(const float* __restrict__ zin,
                                             float* __restrict__ zout,
                                             const int* __restrict__ off,
                                             const int* __restrict__ eidx){
  int t = threadIdx.x;
  int node = blockIdx.x*8 + (t >> 5);
  int c = (t & 31)*4;
  int s = off[node], e = off[node+1];
  float a0=0.f, a1=0.f, a2=0.f, a3=0.f;
  for (int j = s; j < e; ++j){
    f4 v = *(const f4*)(zin + (size_t)eidx[j]*128 + c);
    a0 += v.x; a1 += v.y; a2 += v.z; a3 += v.w;
  }
  f4 r; r.x=a0; r.y=a1; r.z=a2; r.w=a3;
  *(f4*)(zout + (size_t)node*128 + c) = r;
}

// out = [feat_a, deg*feat_a, z0, z1, z2] @ Wcat + biases   (f32)
__global__ __launch_bounds__(256) void proj_all(
    const float* __restrict__ feat_a, const float* __restrict__ deg,
    const float* __restrict__ z0, const float* __restrict__ z1, const float* __restrict__ z2,
    const float* __restrict__ W_prev, const float* __restrict__ W_deg, const float* __restrict__ W_r,
    const float* __restrict__ b_prev, const float* __restrict__ b_deg,
    const float* __restrict__ b_r, const float* __restrict__ b_fuse,
    float* __restrict__ out)
{
  __shared__ float Xs[32][64];
  __shared__ float Ws[64][128];
  int t = threadIdx.x;
  int rbase = blockIdx.x*32;
  int o0 = (t & 15)*8, r0 = (t >> 4)*2;
  float acc[2][8] = {};
  for (int p = 0; p < 10; ++p){
    int seg = p >> 1, half = p & 1;
    {
      int row = t >> 3, e8 = t & 7;
      const float* bp = (seg <= 1) ? feat_a : (seg == 2) ? z0 : (seg == 3) ? z1 : z2;
      const float* sp = bp + (size_t)(rbase+row)*128 + half*64 + e8*8;
      f4 v0 = *(const f4*)sp;
      f4 v1 = *(const f4*)(sp+4);
      if (seg == 1){
        float d = deg[rbase+row];
        v0 *= d; v1 *= d;
      }
      *(f4*)&Xs[row][e8*8]   = v0;
      *(f4*)&Xs[row][e8*8+4] = v1;
    }
    #pragma unroll
    for (int it = 0; it < 8; ++it){
      int lin = it*1024 + t*4;
      int wr = lin >> 7, wc = lin & 127;
      int ksrc = p*64 + wr;
      int sg = ksrc >> 7, kin = ksrc & 127;
      const float* wp = (sg == 0) ? W_prev : (sg == 1) ? W_deg : (W_r + (size_t)(sg-2)*16384);
      *(f4*)&Ws[wr][wc] = *(const f4*)(wp + kin*128 + wc);
    }
    __syncthreads();
    #pragma unroll 8
    for (int kk = 0; kk < 64; ++kk){
      float x0 = Xs[r0][kk], x1 = Xs[r0+1][kk];
      f4 wa = *(const f4*)&Ws[kk][o0];
      f4 wb = *(const f4*)&Ws[kk][o0+4];
      acc[0][0]=fmaf(x0,wa.x,acc[0][0]); acc[0][1]=fmaf(x0,wa.y,acc[0][1]);
      acc[0][2]=fmaf(x0,wa.z,acc[0][2]); acc[0][3]=fmaf(x0,wa.w,acc[0][3]);
      acc[0][4]=fmaf(x0,wb.x,acc[0][4]); acc[0][5]=fmaf(x0,wb.y,acc[0][5]);
      acc[0][6]=fmaf(x0,wb.z,acc[0][6]); acc[0][7]=fmaf(x0,wb.w,acc[0][7]);
      acc[1][0]=fmaf(x1,wa.x,acc[1][0]); acc[1][1]=fmaf(x1,wa.y,acc[1][1]);
      acc[1][2]=fmaf(x1,wa.z,acc[1][2]); acc[1][3]=fmaf(x1,wa.w,acc[1][3]);
      acc[1][4]=fmaf(x1,wb.x,acc[1][4]); acc[1][5]=fmaf(x1,wb.y,acc[1][5]);
      acc[1][6]=fmaf(x1,wb.z,acc[1][6]); acc[1][7]=fmaf(x1,wb.w,acc[1][7]);
    }
    __syncthreads();
  }
  #pragma unroll
  for (int i = 0; i < 2; ++i){
    int r = rbase + r0 + i;
    #pragma unroll
    for (int j = 0; j < 8; ++j){
      int o = o0 + j;
      float bias = b_prev[o] + b_deg[o] + b_fuse[o] + b_r[o] + b_r[128+o] + b_r[256+o];
      out[(size_t)r*128 + o] = acc[i][j] + bias;
    }
  }
}

// C += pm_pd_flat(8192x32768 f32->bf16) @ Bp(32768x128 bf16)
// NO LDS, NO barriers: A streamed nontemporal from HBM, B fragments loaded
// coalesced (1KB/wave/instr) from L2-resident Bpack. BM=128, KSPLIT=16, grid 1024.
__global__ __launch_bounds__(256) void fuse_gemm(const float* __restrict__ A,
                                                 const char* __restrict__ Bpack,
                                                 float* __restrict__ out){
  int b = blockIdx.x;
  int rowtile = b & 63, kc = b >> 6;             // 64 rowtiles x 16 kc; consecutive blocks share kc
  int t = threadIdx.x, w = t >> 6, l = t & 63;
  int lr = l & 15, lk = l >> 4;
  int row0 = rowtile*128 + w*32 + lr;
  const float* a0p = A + (size_t)row0*K2 + kc*2048 + lk*8;
  const float* a1p = a0p + (size_t)16*K2;
  const char* bp = Bpack + (size_t)(kc*64)*8192 + lr*64 + lk*16;
  f32x4 acc[2][8] = {};
  for (int tile = 0; tile < 64; ++tile){         // 64 k32-steps (2048 k per block)
    const float* pa0 = a0p + tile*32;
    const float* pa1 = a1p + tile*32;
    f4 x0 = __builtin_nontemporal_load((const f4*)pa0);
    f4 x1 = __builtin_nontemporal_load((const f4*)pa0 + 1);
    f4 y0 = __builtin_nontemporal_load((const f4*)pa1);
    f4 y1 = __builtin_nontemporal_load((const f4*)pa1 + 1);
    bf16x8 a0 = cvt8t(x0, x1);
    bf16x8 a1 = cvt8t(y0, y1);
    const char* bt = bp + (size_t)tile*8192;
    #pragma unroll
    for (int cf = 0; cf < 8; ++cf){
      bf16x8 bfr = *(const bf16x8*)(bt + cf*1024);
      acc[0][cf] = __builtin_amdgcn_mfma_f32_16x16x32_bf16(a0, bfr, acc[0][cf], 0, 0, 0);
      acc[1][cf] = __builtin_amdgcn_mfma_f32_16x16x32_bf16(a1, bfr, acc[1][cf], 0, 0, 0);
    }
  }
  int orow = rowtile*128 + w*32 + lk*4;
  #pragma unroll
  for (int rf = 0; rf < 2; ++rf){
    #pragma unroll
    for (int cf = 0; cf < 8; ++cf){
      #pragma unroll
      for (int j = 0; j < 4; ++j){
        unsafeAtomicAdd(out + (size_t)(orow + rf*16 + j)*128 + cf*16 + lr, acc[rf][cf][j]);
      }
    }
  }
}

// BatchNorm stats with half-ReLU on read; row-contiguous reads
__global__ __launch_bounds__(256) void colstats(const float* __restrict__ acc,
                                                float* __restrict__ gsum,
                                                float* __restrict__ gsumsq){
  __shared__ float s1[8][128], s2[8][128];
  int t = threadIdx.x;
  int c4 = (t & 31)*4, rsub = t >> 5;
  int rbase = blockIdx.x*32;
  f4 sum = {0,0,0,0}, sq = {0,0,0,0};
  #pragma unroll
  for (int i = 0; i < 4; ++i){
    f4 v = *(const f4*)(acc + (size_t)(rbase + rsub + i*8)*128 + c4);
    if (c4 >= 64){
      v.x=fmaxf(v.x,0.f); v.y=fmaxf(v.y,0.f); v.z=fmaxf(v.z,0.f); v.w=fmaxf(v.w,0.f);
    }
    sum += v; sq += v*v;
  }
  *(f4*)&s1[rsub][c4] = sum;
  *(f4*)&s2[rsub][c4] = sq;
  __syncthreads();
  if (t < 128){
    float a = 0.f, b2 = 0.f;
    #pragma unroll
    for (int r = 0; r < 8; ++r){ a += s1[r][t]; b2 += s2[r][t]; }
    unsafeAtomicAdd(gsum + t, a);
    unsafeAtomicAdd(gsumsq + t, b2);
  }
}

__global__ void bn_final(const float* __restrict__ gsum, const float* __restrict__ gsumsq,
                         const float* __restrict__ gamma, const float* __restrict__ beta,
                         float* __restrict__ scale, float* __restrict__ shift){
  int c = threadIdx.x;
  float mean = gsum[c] * (1.f/8192.f);
  float var  = gsumsq[c] * (1.f/8192.f) - mean*mean;
  float rstd = rsqrtf(var + 1e-5f);
  float sc = rstd * gamma[c];
  scale[c] = sc;
  shift[c] = beta[c] - mean*sc;
}

__global__ __launch_bounds__(256) void bn_apply(float* __restrict__ out,
                                                const float* __restrict__ scale,
                                                const float* __restrict__ shift){
  int i = blockIdx.x*256 + threadIdx.x;
  int j = i & 31;
  f4* o4 = (f4*)out;
  f4 v = o4[i];
  if (j >= 16){
    v.x=fmaxf(v.x,0.f); v.y=fmaxf(v.y,0.f); v.z=fmaxf(v.z,0.f); v.w=fmaxf(v.w,0.f);
  }
  f4 sc = *(const f4*)(scale + j*4);
  f4 sh = *(const f4*)(shift + j*4);
  v.x = fmaf(v.x,sc.x,sh.x); v.y = fmaf(v.y,sc.y,sh.y);
  v.z = fmaf(v.z,sc.z,sh.z); v.w = fmaf(v.w,sc.w,sh.w);
  o4[i] = v;
}

extern "C" void kernel_launch(void* const* d_in, const int* in_sizes, int n_in,
                              void* d_out, int out_size, void* d_ws, size_t ws_size,
                              hipStream_t stream) {
  const float* feat_a = (const float*)d_in[0];
  const float* feat_b = (const float*)d_in[1];
  const float* deg    = (const float*)d_in[2];
  const float* pm_pd  = (const float*)d_in[3];
  const int*   src    = (const int*)d_in[4];
  const int*   dst    = (const int*)d_in[5];
  const float* W_prev = (const float*)d_in[6];
  const float* b_prev = (const float*)d_in[7];
  const float* W_deg  = (const float*)d_in[8];
  const float* b_deg  = (const float*)d_in[9];
  const float* W_r    = (const float*)d_in[10];
  const float* b_r    = (const float*)d_in[11];
  const float* W_fuse = (const float*)d_in[12];
  const float* b_fuse = (const float*)d_in[13];
  const float* gamma  = (const float*)d_in[14];
  const float* beta   = (const float*)d_in[15];
  float* out = (float*)d_out;

  char* w = (char*)d_ws;
  char*  Bpack  = (char*) (w + 0);          // 8 MB fragment-ordered B'
  float* z0     = (float*)(w + 8388608);
  float* z1     = (float*)(w + 12582912);
  float* ztmp   = (float*)(w + 16777216);
  float* z2     = (float*)(w + 20971520);
  u16*   WfT    = (u16*)  (w + 25165824);
  int*   hist   = (int*)  (w + 25231360);
  int*   off    = (int*)  (w + 25264128);
  int*   cursor = (int*)  (w + 25296912);
  int*   eidx   = (int*)  (w + 25329680);
  float* gsum   = (float*)(w + 25853968);
  float* gsumsq = gsum + 128;
  float* scale  = (float*)(w + 25854992);
  float* shift  = (float*)(w + 25855504);
  if (ws_size < (size_t)25856016) return;

  hipMemsetAsync(hist, 0, NN*sizeof(int), stream);
  hipMemsetAsync(gsum, 0, 256*sizeof(float), stream);

  wft_k<<<256, 128, 0, stream>>>(W_fuse, WfT);
  prep_bpt<<<MM/32, 128, 0, stream>>>(feat_b, WfT, Bpack);

  hist_k<<<EE/256, 256, 0, stream>>>(dst, hist);
  scan_k<<<1, 256, 0, stream>>>(hist, off, cursor);
  fill_k<<<EE/256, 256, 0, stream>>>(src, dst, cursor, eidx);

  agg_k<<<NN/8, 256, 0, stream>>>(feat_a, z0, off, eidx);
  agg_k<<<NN/8, 256, 0, stream>>>(z0, z1, off, eidx);
  agg_k<<<NN/8, 256, 0, stream>>>(z1, ztmp, off, eidx);
  agg_k<<<NN/8, 256, 0, stream>>>(ztmp, z2, off, eidx);

  proj_all<<<NN/32, 256, 0, stream>>>(feat_a, deg, z0, z1, z2,
                                      W_prev, W_deg, W_r, b_prev, b_deg, b_r, b_fuse, out);

  fuse_gemm<<<1024, 256, 0, stream>>>(pm_pd, Bpack, out);

  colstats<<<NN/32, 256, 0, stream>>>(out, gsum, gsumsq);
  bn_final<<<1, 128, 0, stream>>>(gsum, gsumsq, gamma, beta, scale, shift);
  bn_apply<<<NN*128/4/256, 256, 0, stream>>>(out, scale, shift);
}

// Round 6
// 663.508 us; speedup vs baseline: 1.0183x; 1.0183x over previous
//
#include <hip/hip_runtime.h>
#include <hip/hip_bf16.h>

#define NN 8192
#define MM 16384
#define EE 131072
#define K2 32768   // 2*MM, interleaved-channel K dim

typedef unsigned short u16;
typedef __attribute__((ext_vector_type(8))) short bf16x8;
typedef __attribute__((ext_vector_type(4))) float f32x4;
typedef __attribute__((ext_vector_type(4))) float f4;   // native clang vector (nontemporal-safe)

__device__ __forceinline__ u16 f2bf(float f){
  union { float f; unsigned u; } x; x.f = f;
  return (u16)((x.u + 0x7FFFu + ((x.u >> 16) & 1u)) >> 16);   // RNE truncate
}

__device__ __forceinline__ bf16x8 cvt8(f4 a, f4 b){
  bf16x8 r;
  r[0]=(short)f2bf(a.x); r[1]=(short)f2bf(a.y);
  r[2]=(short)f2bf(a.z); r[3]=(short)f2bf(a.w);
  r[4]=(short)f2bf(b.x); r[5]=(short)f2bf(b.y);
  r[6]=(short)f2bf(b.z); r[7]=(short)f2bf(b.w);
  return r;
}

// ---------------- WfT[co][j] = bf16(W_fuse[(co>>7)*128 + j][co&127]) ----------------
__global__ void wft_k(const float* __restrict__ W_fuse, u16* __restrict__ WfT){
  int co = blockIdx.x, j = threadIdx.x;          // 256 blocks x 128 threads
  int c = co >> 7, o = co & 127;
  WfT[co*128 + j] = f2bf(W_fuse[(c*128 + j)*128 + o]);
}

// ---------------- BpT[o][2m+c] = bf16( sum_j feat_b[m][j] * W_fuse[c*128+j][o] ) ------
// MFMA GEMM: A = feat_b (16384x128), B = WfT (cols = (c,o) pairs), store transposed+interleaved.
__global__ __launch_bounds__(256) void prep_bpt(const float* __restrict__ feat_b,
                                                const u16* __restrict__ WfT,
                                                u16* __restrict__ BpT){
  int t = threadIdx.x, w = t >> 6, l = t & 63;
  int lr = l & 15, lk = l >> 4;
  int mrow = blockIdx.x*64 + w*16;               // 256 blocks, wave = 16 rows
  f32x4 acc[16] = {};
  const float* ap = feat_b + (size_t)(mrow + lr)*128 + lk*8;
  #pragma unroll
  for (int ks = 0; ks < 4; ++ks){
    f4 a0 = *(const f4*)(ap + ks*32);
    f4 a1 = *(const f4*)(ap + ks*32 + 4);
    bf16x8 a = cvt8(a0, a1);
    #pragma unroll
    for (int cf = 0; cf < 16; ++cf){
      bf16x8 b = *(const bf16x8*)(WfT + (cf*16 + lr)*128 + ks*32 + lk*8);
      acc[cf] = __builtin_amdgcn_mfma_f32_16x16x32_bf16(a, b, acc[cf], 0, 0, 0);
    }
  }
  #pragma unroll
  for (int cf = 0; cf < 16; ++cf){
    int co = cf*16 + lr;
    int o = co & 127, c = co >> 7;
    #pragma unroll
    for (int j = 0; j < 4; ++j){
      int m = mrow + lk*4 + j;                   // C/D: row=(lane>>4)*4+reg, col=lane&15
      BpT[(size_t)o*K2 + 2*m + c] = f2bf(acc[cf][j]);
    }
  }
}

// ---------------- CSR build: histogram / scan / fill ----------------
__global__ void hist_k(const int* __restrict__ dst, int* __restrict__ hist){
  int e = blockIdx.x*256 + threadIdx.x;
  atomicAdd(hist + dst[e], 1);
}

__global__ void scan_k(const int* __restrict__ hist, int* __restrict__ off,
                       int* __restrict__ cursor){
  __shared__ int part[256];
  int t = threadIdx.x;
  int loc[32]; int s = 0;
  #pragma unroll
  for (int i = 0; i < 32; ++i){ loc[i] = hist[t*32 + i]; s += loc[i]; }
  part[t] = s;
  __syncthreads();
  for (int d = 1; d < 256; d <<= 1){
    int v = (t >= d) ? part[t-d] : 0;
    __syncthreads();
    part[t] += v;
    __syncthreads();
  }
  int run = (t > 0) ? part[t-1] : 0;
  #pragma unroll
  for (int i = 0; i < 32; ++i){ off[t*32+i] = run; cursor[t*32+i] = run; run += loc[i]; }
  if (t == 255) off[NN] = run;
}

__global__ void fill_k(const int* __restrict__ src, const int* __restrict__ dst,
                       int* __restrict__ cursor, int* __restrict__ eidx){
  int e = blockIdx.x*256 + threadIdx.x;
  int pos = atomicAdd(cursor + dst[e], 1);
  eidx[pos] = src[e];
}

// ---------------- agg: zout[n] = sum_{e: dst[e]=n} zin[src[e]]  (gather, no float atomics)
__global__ __launch_bounds__(256) void agg_k(const float* __restrict__ zin,
                                             float* __restrict__ zout,
                                             const int* __restrict__ off,
                                             const int* __restrict__ eidx){
  int t = threadIdx.x;
  int node = blockIdx.x*8 + (t >> 5);            // 1024 blocks x 8 nodes
  int c = (t & 31)*4;
  int s = off[node], e = off[node+1];
  float a0=0.f, a1=0.f, a2=0.f, a3=0.f;
  for (int j = s; j < e; ++j){
    f4 v = *(const f4*)(zin + (size_t)eidx[j]*128 + c);
    a0 += v.x; a1 += v.y; a2 += v.z; a3 += v.w;
  }
  f4 r; r.x=a0; r.y=a1; r.z=a2; r.w=a3;
  *(f4*)(zout + (size_t)node*128 + c) = r;
}

// ---------------- small projections (f32, tiled):  out = [feat_a, deg*feat_a, z0, z1, z2] @ Wcat + biases
__global__ __launch_bounds__(256) void proj_all(
    const float* __restrict__ feat_a, const float* __restrict__ deg,
    const float* __restrict__ z0, const float* __restrict__ z1, const float* __restrict__ z2,
    const float* __restrict__ W_prev, const float* __restrict__ W_deg, const float* __restrict__ W_r,
    const float* __restrict__ b_prev, const float* __restrict__ b_deg,
    const float* __restrict__ b_r, const float* __restrict__ b_fuse,
    float* __restrict__ out)
{
  __shared__ float Xs[32][64];
  __shared__ float Ws[64][128];
  int t = threadIdx.x;
  int rbase = blockIdx.x*32;                     // 256 blocks
  int o0 = (t & 15)*8, r0 = (t >> 4)*2;
  float acc[2][8] = {};
  for (int p = 0; p < 10; ++p){                  // 10 phases of K=64 over Kcat=640
    int seg = p >> 1, half = p & 1;
    {
      int row = t >> 3, e8 = t & 7;
      const float* bp = (seg <= 1) ? feat_a : (seg == 2) ? z0 : (seg == 3) ? z1 : z2;
      const float* sp = bp + (size_t)(rbase+row)*128 + half*64 + e8*8;
      f4 v0 = *(const f4*)sp;
      f4 v1 = *(const f4*)(sp+4);
      if (seg == 1){
        float d = deg[rbase+row];
        v0 *= d; v1 *= d;
      }
      *(f4*)&Xs[row][e8*8]   = v0;
      *(f4*)&Xs[row][e8*8+4] = v1;
    }
    #pragma unroll
    for (int it = 0; it < 8; ++it){
      int lin = it*1024 + t*4;
      int wr = lin >> 7, wc = lin & 127;
      int ksrc = p*64 + wr;
      int sg = ksrc >> 7, kin = ksrc & 127;
      const float* wp = (sg == 0) ? W_prev : (sg == 1) ? W_deg : (W_r + (size_t)(sg-2)*16384);
      *(f4*)&Ws[wr][wc] = *(const f4*)(wp + kin*128 + wc);
    }
    __syncthreads();
    #pragma unroll 8
    for (int kk = 0; kk < 64; ++kk){
      float x0 = Xs[r0][kk], x1 = Xs[r0+1][kk];
      f4 wa = *(const f4*)&Ws[kk][o0];
      f4 wb = *(const f4*)&Ws[kk][o0+4];
      acc[0][0]=fmaf(x0,wa.x,acc[0][0]); acc[0][1]=fmaf(x0,wa.y,acc[0][1]);
      acc[0][2]=fmaf(x0,wa.z,acc[0][2]); acc[0][3]=fmaf(x0,wa.w,acc[0][3]);
      acc[0][4]=fmaf(x0,wb.x,acc[0][4]); acc[0][5]=fmaf(x0,wb.y,acc[0][5]);
      acc[0][6]=fmaf(x0,wb.z,acc[0][6]); acc[0][7]=fmaf(x0,wb.w,acc[0][7]);
      acc[1][0]=fmaf(x1,wa.x,acc[1][0]); acc[1][1]=fmaf(x1,wa.y,acc[1][1]);
      acc[1][2]=fmaf(x1,wa.z,acc[1][2]); acc[1][3]=fmaf(x1,wa.w,acc[1][3]);
      acc[1][4]=fmaf(x1,wb.x,acc[1][4]); acc[1][5]=fmaf(x1,wb.y,acc[1][5]);
      acc[1][6]=fmaf(x1,wb.z,acc[1][6]); acc[1][7]=fmaf(x1,wb.w,acc[1][7]);
    }
    __syncthreads();
  }
  #pragma unroll
  for (int i = 0; i < 2; ++i){
    int r = rbase + r0 + i;
    #pragma unroll
    for (int j = 0; j < 8; ++j){
      int o = o0 + j;
      float bias = b_prev[o] + b_deg[o] + b_fuse[o] + b_r[o] + b_r[128+o] + b_r[256+o];
      out[(size_t)r*128 + o] = acc[i][j] + bias;
    }
  }
}

// ---------------- the big one: C += pm_pd_flat(8192x32768 f32->bf16) @ Bp(32768x128 bf16)
__global__ __launch_bounds__(256, 2) void fuse_gemm(const float* __restrict__ A,
                                                    const u16* __restrict__ BpT,
                                                    float* __restrict__ out){
  __shared__ u16 Bs[128*64];                     // [o][kk] bf16, 16B-slot XOR-swizzled
  int b = blockIdx.x;
  int rowtile = b & 63, kc = b >> 6;             // 64 rowtiles x KSPLIT=8; adjacent blocks share kc slice
  int t = threadIdx.x, w = t >> 6, l = t & 63;
  int lr = l & 15, lk = l >> 4;
  size_t kbase = (size_t)kc*4096;
  int row0 = rowtile*128 + w*32 + lr;
  const float* a0p = A + (size_t)row0*K2 + kbase + lk*8;
  const float* a1p = a0p + (size_t)16*K2;
  f32x4 acc[2][8] = {};
  for (int tile = 0; tile < 64; ++tile){         // 4096 / BK=64
    size_t kt = kbase + tile*64;
    #pragma unroll
    for (int pp = 0; pp < 4; ++pp){              // stage B tile: 128 o x 64 kk
      int q = pp*256 + t;
      int o = q >> 3, oct = q & 7;
      uint4 v = *(const uint4*)(BpT + (size_t)o*K2 + kt + oct*8);
      *(uint4*)((char*)Bs + o*128 + ((oct ^ (o & 7)) << 4)) = v;
    }
    __syncthreads();
    #pragma unroll
    for (int s = 0; s < 2; ++s){
      const float* pa0 = a0p + tile*64 + s*32;
      const float* pa1 = a1p + tile*64 + s*32;
      f4 x0 = __builtin_nontemporal_load((const f4*)pa0);
      f4 x1 = __builtin_nontemporal_load((const f4*)pa0 + 1);
      f4 y0 = __builtin_nontemporal_load((const f4*)pa1);
      f4 y1 = __builtin_nontemporal_load((const f4*)pa1 + 1);
      bf16x8 a0 = cvt8(x0, x1);
      bf16x8 a1 = cvt8(y0, y1);
      int khalf = s*4 + lk;
      #pragma unroll
      for (int cf = 0; cf < 8; ++cf){
        int o = cf*16 + lr;
        bf16x8 bfr = *(const bf16x8*)((char*)Bs + o*128 + ((khalf ^ (o & 7)) << 4));
        acc[0][cf] = __builtin_amdgcn_mfma_f32_16x16x32_bf16(a0, bfr, acc[0][cf], 0, 0, 0);
        acc[1][cf] = __builtin_amdgcn_mfma_f32_16x16x32_bf16(a1, bfr, acc[1][cf], 0, 0, 0);
      }
    }
    __syncthreads();
  }
  int orow = rowtile*128 + w*32 + lk*4;
  #pragma unroll
  for (int rf = 0; rf < 2; ++rf){
    #pragma unroll
    for (int cf = 0; cf < 8; ++cf){
      #pragma unroll
      for (int j = 0; j < 4; ++j){
        unsafeAtomicAdd(out + (size_t)(orow + rf*16 + j)*128 + cf*16 + lr, acc[rf][cf][j]);
      }
    }
  }
}

// ---------------- BatchNorm (training stats) with half-ReLU on read ----------------
__global__ __launch_bounds__(256) void colstats(const float* __restrict__ acc,
                                                float* __restrict__ gsum,
                                                float* __restrict__ gsumsq){
  __shared__ float s1[256], s2[256];
  int t = threadIdx.x;
  int col = t & 127, rsub = t >> 7;
  int rbase = blockIdx.x*64;                     // 128 blocks
  float sum = 0.f, sq = 0.f;
  #pragma unroll 4
  for (int i = 0; i < 32; ++i){
    float v = acc[(size_t)(rbase + rsub + i*2)*128 + col];
    if (col >= 64) v = fmaxf(v, 0.f);
    sum += v; sq = fmaf(v, v, sq);
  }
  s1[t] = sum; s2[t] = sq;
  __syncthreads();
  if (t < 128){
    unsafeAtomicAdd(gsum + col,   s1[t] + s1[t+128]);
    unsafeAtomicAdd(gsumsq + col, s2[t] + s2[t+128]);
  }
}

__global__ void bn_final(const float* __restrict__ gsum, const float* __restrict__ gsumsq,
                         const float* __restrict__ gamma, const float* __restrict__ beta,
                         float* __restrict__ scale, float* __restrict__ shift){
  int c = threadIdx.x;                           // 1 block x 128
  float mean = gsum[c] * (1.f/8192.f);
  float var  = gsumsq[c] * (1.f/8192.f) - mean*mean;
  float rstd = rsqrtf(var + 1e-5f);
  float sc = rstd * gamma[c];
  scale[c] = sc;
  shift[c] = beta[c] - mean*sc;
}

__global__ __launch_bounds__(256) void bn_apply(float* __restrict__ out,
                                                const float* __restrict__ scale,
                                                const float* __restrict__ shift){
  int i = blockIdx.x*256 + threadIdx.x;          // over 8192*32 float4s
  int j = i & 31;
  f4* o4 = (f4*)out;
  f4 v = o4[i];
  if (j >= 16){
    v.x=fmaxf(v.x,0.f); v.y=fmaxf(v.y,0.f); v.z=fmaxf(v.z,0.f); v.w=fmaxf(v.w,0.f);
  }
  f4 sc = *(const f4*)(scale + j*4);
  f4 sh = *(const f4*)(shift + j*4);
  v.x = fmaf(v.x,sc.x,sh.x); v.y = fmaf(v.y,sc.y,sh.y);
  v.z = fmaf(v.z,sc.z,sh.z); v.w = fmaf(v.w,sc.w,sh.w);
  o4[i] = v;
}

extern "C" void kernel_launch(void* const* d_in, const int* in_sizes, int n_in,
                              void* d_out, int out_size, void* d_ws, size_t ws_size,
                              hipStream_t stream) {
  const float* feat_a = (const float*)d_in[0];
  const float* feat_b = (const float*)d_in[1];
  const float* deg    = (const float*)d_in[2];
  const float* pm_pd  = (const float*)d_in[3];
  const int*   src    = (const int*)d_in[4];
  const int*   dst    = (const int*)d_in[5];
  const float* W_prev = (const float*)d_in[6];
  const float* b_prev = (const float*)d_in[7];
  const float* W_deg  = (const float*)d_in[8];
  const float* b_deg  = (const float*)d_in[9];
  const float* W_r    = (const float*)d_in[10];
  const float* b_r    = (const float*)d_in[11];
  const float* W_fuse = (const float*)d_in[12];
  const float* b_fuse = (const float*)d_in[13];
  const float* gamma  = (const float*)d_in[14];
  const float* beta   = (const float*)d_in[15];
  float* out = (float*)d_out;

  // workspace layout (bytes), all 16B-aligned; total ~25.9 MB
  char* w = (char*)d_ws;
  u16*   BpT    = (u16*)  (w + 0);          // 128*32768*2    = 8388608
  float* z0     = (float*)(w + 8388608);    // 4 MB
  float* z1     = (float*)(w + 12582912);
  float* ztmp   = (float*)(w + 16777216);
  float* z2     = (float*)(w + 20971520);
  u16*   WfT    = (u16*)  (w + 25165824);   // 256*128*2 = 65536
  int*   hist   = (int*)  (w + 25231360);   // 32768
  int*   off    = (int*)  (w + 25264128);   // 8193*4 -> pad 32784
  int*   cursor = (int*)  (w + 25296912);   // 32768
  int*   eidx   = (int*)  (w + 25329680);   // 524288
  float* gsum   = (float*)(w + 25853968);   // 128
  float* gsumsq = gsum + 128;               // 128 (zeroed together: 1024 B)
  float* scale  = (float*)(w + 25854992);
  float* shift  = (float*)(w + 25855504);
  if (ws_size < (size_t)25856016) return;   // loud failure (poison stays) if ws too small

  hipMemsetAsync(hist, 0, NN*sizeof(int), stream);
  hipMemsetAsync(gsum, 0, 256*sizeof(float), stream);

  // fuse-GEMM prep: B' = interleaved [feat_b @ Wf_top ; feat_b @ Wf_bot], transposed bf16
  wft_k<<<256, 128, 0, stream>>>(W_fuse, WfT);
  prep_bpt<<<MM/64, 256, 0, stream>>>(feat_b, WfT, BpT);

  // CSR build (counting sort by dst)
  hist_k<<<EE/256, 256, 0, stream>>>(dst, hist);
  scan_k<<<1, 256, 0, stream>>>(hist, off, cursor);
  fill_k<<<EE/256, 256, 0, stream>>>(src, dst, cursor, eidx);

  // aggregate_radius: z0 = A f, z1 = A^2 f, z2 = A^4 f
  agg_k<<<NN/8, 256, 0, stream>>>(feat_a, z0, off, eidx);
  agg_k<<<NN/8, 256, 0, stream>>>(z0, z1, off, eidx);
  agg_k<<<NN/8, 256, 0, stream>>>(z1, ztmp, off, eidx);
  agg_k<<<NN/8, 256, 0, stream>>>(ztmp, z2, off, eidx);

  // acc = prev_proj + deg_proj + radius_proj + all biases (writes every cell of d_out)
  proj_all<<<NN/32, 256, 0, stream>>>(feat_a, deg, z0, z1, z2,
                                      W_prev, W_deg, W_r, b_prev, b_deg, b_r, b_fuse, out);

  // acc += pm_pd-fusion (HBM-bound: streams 1.07 GB once)
  fuse_gemm<<<512, 256, 0, stream>>>(pm_pd, BpT, out);

  // half-ReLU + BatchNorm (training-mode batch stats), in place
  colstats<<<NN/64, 256, 0, stream>>>(out, gsum, gsumsq);
  bn_final<<<1, 128, 0, stream>>>(gsum, gsumsq, gamma, beta, scale, shift);
  bn_apply<<<NN*128/4/256, 256, 0, stream>>>(out, scale, shift);
}

// Round 7
// 427.265 us; speedup vs baseline: 1.5813x; 1.5529x over previous
//
#include <hip/hip_runtime.h>
#include <hip/hip_bf16.h>

#define NN 8192
#define MM 16384
#define EE 131072
#define K2 32768

typedef unsigned short u16;
typedef unsigned int u32;
typedef __attribute__((ext_vector_type(8))) short bf16x8;
typedef __attribute__((ext_vector_type(4))) float f32x4;
typedef __attribute__((ext_vector_type(4))) float f4;

__device__ __forceinline__ u16 f2bf(float f){
  union { float f; unsigned u; } x; x.f = f;
  return (u16)((x.u + 0x7FFFu + ((x.u >> 16) & 1u)) >> 16);   // RNE
}

__device__ __forceinline__ bf16x8 cvt8(f4 a, f4 b){            // RNE path (prep kernels)
  bf16x8 r;
  r[0]=(short)f2bf(a.x); r[1]=(short)f2bf(a.y);
  r[2]=(short)f2bf(a.z); r[3]=(short)f2bf(a.w);
  r[4]=(short)f2bf(b.x); r[5]=(short)f2bf(b.y);
  r[6]=(short)f2bf(b.z); r[7]=(short)f2bf(b.w);
  return r;
}

// truncating pack: one v_perm_b32 per 2 floats (hot path: fuse_gemm A-convert)
__device__ __forceinline__ bf16x8 cvt8t(f4 a, f4 b){
  union { u32 u[4]; bf16x8 v; } r;
  r.u[0] = __builtin_amdgcn_perm(__float_as_uint(a.y), __float_as_uint(a.x), 0x07060302u);
  r.u[1] = __builtin_amdgcn_perm(__float_as_uint(a.w), __float_as_uint(a.z), 0x07060302u);
  r.u[2] = __builtin_amdgcn_perm(__float_as_uint(b.y), __float_as_uint(b.x), 0x07060302u);
  r.u[3] = __builtin_amdgcn_perm(__float_as_uint(b.w), __float_as_uint(b.z), 0x07060302u);
  return r.v;
}

// WfT[co][j] = bf16(W_fuse[(co>>7)*128 + j][co&127])
__global__ void wft_k(const float* __restrict__ W_fuse, u16* __restrict__ WfT){
  int co = blockIdx.x, j = threadIdx.x;
  int c = co >> 7, o = co & 127;
  WfT[co*128 + j] = f2bf(W_fuse[(c*128 + j)*128 + o]);
}

// BpT[o][2m+c] = bf16(sum_j feat_b[m][j] * W_fuse[c*128+j][o]); packed u32 (c0|c1<<16), uint4 stores
__global__ __launch_bounds__(128) void prep_bpt(const float* __restrict__ feat_b,
                                                const u16* __restrict__ WfT,
                                                u32* __restrict__ BpT32){
  int t = threadIdx.x, w = t >> 6, l = t & 63;
  int lr = l & 15, lk = l >> 4;
  int mrow = blockIdx.x*32 + w*16;               // 512 blocks x 2 waves
  f32x4 acc[16] = {};
  const float* ap = feat_b + (size_t)(mrow + lr)*128 + lk*8;
  #pragma unroll
  for (int ks = 0; ks < 4; ++ks){
    f4 a0 = *(const f4*)(ap + ks*32);
    f4 a1 = *(const f4*)(ap + ks*32 + 4);
    bf16x8 a = cvt8(a0, a1);
    #pragma unroll
    for (int cf = 0; cf < 16; ++cf){
      bf16x8 b = *(const bf16x8*)(WfT + (cf*16 + lr)*128 + ks*32 + lk*8);
      acc[cf] = __builtin_amdgcn_mfma_f32_16x16x32_bf16(a, b, acc[cf], 0, 0, 0);
    }
  }
  #pragma unroll
  for (int cf = 0; cf < 8; ++cf){
    int o = cf*16 + lr;
    uint4 v;
    v.x = (u32)f2bf(acc[cf][0]) | ((u32)f2bf(acc[cf+8][0]) << 16);
    v.y = (u32)f2bf(acc[cf][1]) | ((u32)f2bf(acc[cf+8][1]) << 16);
    v.z = (u32)f2bf(acc[cf][2]) | ((u32)f2bf(acc[cf+8][2]) << 16);
    v.w = (u32)f2bf(acc[cf][3]) | ((u32)f2bf(acc[cf+8][3]) << 16);
    *(uint4*)(BpT32 + (size_t)o*16384 + mrow + lk*4) = v;
  }
}

// CSR build
__global__ void hist_k(const int* __restrict__ dst, int* __restrict__ hist){
  int e = blockIdx.x*256 + threadIdx.x;
  atomicAdd(hist + dst[e], 1);
}

__global__ void scan_k(const int* __restrict__ hist, int* __restrict__ off,
                       int* __restrict__ cursor){
  __shared__ int part[256];
  int t = threadIdx.x;
  int loc[32]; int s = 0;
  #pragma unroll
  for (int i = 0; i < 32; ++i){ loc[i] = hist[t*32 + i]; s += loc[i]; }
  part[t] = s;
  __syncthreads();
  for (int d = 1; d < 256; d <<= 1){
    int v = (t >= d) ? part[t-d] : 0;
    __syncthreads();
    part[t] += v;
    __syncthreads();
  }
  int run = (t > 0) ? part[t-1] : 0;
  #pragma unroll
  for (int i = 0; i < 32; ++i){ off[t*32+i] = run; cursor[t*32+i] = run; run += loc[i]; }
  if (t == 255) off[NN] = run;
}

__global__ void fill_k(const int* __restrict__ src, const int* __restrict__ dst,
                       int* __restrict__ cursor, int* __restrict__ eidx){
  int e = blockIdx.x*256 + threadIdx.x;
  int pos = atomicAdd(cursor + dst[e], 1);
  eidx[pos] = src[e];
}

// agg: zout[n] = sum_{e: dst[e]=n} zin[src[e]]
__global__ __launch_bounds__(256) void agg_k(const float* __restrict__ zin,
                                             float* __restrict__ zout,
                                             const int* __restrict__ off,
                                             const int* __restrict__ eidx){
  int t = threadIdx.x;
  int node = blockIdx.x*8 + (t >> 5);
  int c = (t & 31)*4;
  int s = off[node], e = off[node+1];
  float a0=0.f, a1=0.f, a2=0.f, a3=0.f;
  for (int j = s; j < e; ++j){
    f4 v = *(const f4*)(zin + (size_t)eidx[j]*128 + c);
    a0 += v.x; a1 += v.y; a2 += v.z; a3 += v.w;
  }
  f4 r; r.x=a0; r.y=a1; r.z=a2; r.w=a3;
  *(f4*)(zout + (size_t)node*128 + c) = r;
}

// out = [feat_a, deg*feat_a, z0, z1, z2] @ Wcat + biases   (f32)
__global__ __launch_bounds__(256) void proj_all(
    const float* __restrict__ feat_a, const float* __restrict__ deg,
    const float* __restrict__ z0, const float* __restrict__ z1, const float* __restrict__ z2,
    const float* __restrict__ W_prev, const float* __restrict__ W_deg, const float* __restrict__ W_r,
    const float* __restrict__ b_prev, const float* __restrict__ b_deg,
    const float* __restrict__ b_r, const float* __restrict__ b_fuse,
    float* __restrict__ out)
{
  __shared__ float Xs[32][64];
  __shared__ float Ws[64][128];
  int t = threadIdx.x;
  int rbase = blockIdx.x*32;
  int o0 = (t & 15)*8, r0 = (t >> 4)*2;
  float acc[2][8] = {};
  for (int p = 0; p < 10; ++p){
    int seg = p >> 1, half = p & 1;
    {
      int row = t >> 3, e8 = t & 7;
      const float* bp = (seg <= 1) ? feat_a : (seg == 2) ? z0 : (seg == 3) ? z1 : z2;
      const float* sp = bp + (size_t)(rbase+row)*128 + half*64 + e8*8;
      f4 v0 = *(const f4*)sp;
      f4 v1 = *(const f4*)(sp+4);
      if (seg == 1){
        float d = deg[rbase+row];
        v0 *= d; v1 *= d;
      }
      *(f4*)&Xs[row][e8*8]   = v0;
      *(f4*)&Xs[row][e8*8+4] = v1;
    }
    #pragma unroll
    for (int it = 0; it < 8; ++it){
      int lin = it*1024 + t*4;
      int wr = lin >> 7, wc = lin & 127;
      int ksrc = p*64 + wr;
      int sg = ksrc >> 7, kin = ksrc & 127;
      const float* wp = (sg == 0) ? W_prev : (sg == 1) ? W_deg : (W_r + (size_t)(sg-2)*16384);
      *(f4*)&Ws[wr][wc] = *(const f4*)(wp + kin*128 + wc);
    }
    __syncthreads();
    #pragma unroll 8
    for (int kk = 0; kk < 64; ++kk){
      float x0 = Xs[r0][kk], x1 = Xs[r0+1][kk];
      f4 wa = *(const f4*)&Ws[kk][o0];
      f4 wb = *(const f4*)&Ws[kk][o0+4];
      acc[0][0]=fmaf(x0,wa.x,acc[0][0]); acc[0][1]=fmaf(x0,wa.y,acc[0][1]);
      acc[0][2]=fmaf(x0,wa.z,acc[0][2]); acc[0][3]=fmaf(x0,wa.w,acc[0][3]);
      acc[0][4]=fmaf(x0,wb.x,acc[0][4]); acc[0][5]=fmaf(x0,wb.y,acc[0][5]);
      acc[0][6]=fmaf(x0,wb.z,acc[0][6]); acc[0][7]=fmaf(x0,wb.w,acc[0][7]);
      acc[1][0]=fmaf(x1,wa.x,acc[1][0]); acc[1][1]=fmaf(x1,wa.y,acc[1][1]);
      acc[1][2]=fmaf(x1,wa.z,acc[1][2]); acc[1][3]=fmaf(x1,wa.w,acc[1][3]);
      acc[1][4]=fmaf(x1,wb.x,acc[1][4]); acc[1][5]=fmaf(x1,wb.y,acc[1][5]);
      acc[1][6]=fmaf(x1,wb.z,acc[1][6]); acc[1][7]=fmaf(x1,wb.w,acc[1][7]);
    }
    __syncthreads();
  }
  #pragma unroll
  for (int i = 0; i < 2; ++i){
    int r = rbase + r0 + i;
    #pragma unroll
    for (int j = 0; j < 8; ++j){
      int o = o0 + j;
      float bias = b_prev[o] + b_deg[o] + b_fuse[o] + b_r[o] + b_r[128+o] + b_r[256+o];
      out[(size_t)r*128 + o] = acc[i][j] + bias;
    }
  }
}

// C += pm_pd_flat(8192x32768 f32->bf16) @ Bp(32768x128 bf16)
// R4 structure (BM=128, KSPLIT=8, grid 512, 2 blocks/CU, LDS B-tile) +
// A-register ping-pong prefetch: tile t+1's A-loads issue BEFORE tile t's
// staging barrier, so the vmcnt drain at the barrier covers A-latency too.
__global__ __launch_bounds__(256, 2) void fuse_gemm(const float* __restrict__ A,
                                                    const u16* __restrict__ BpT,
                                                    float* __restrict__ out){
  __shared__ u16 Bs[128*64];
  int b = blockIdx.x;
  int rowtile = b & 63, kc = b >> 6;
  int t = threadIdx.x, w = t >> 6, l = t & 63;
  int lr = l & 15, lk = l >> 4;
  size_t kbase = (size_t)kc*4096;
  int row0 = rowtile*128 + w*32 + lr;
  const float* a0p = A + (size_t)row0*K2 + kbase + lk*8;
  const float* a1p = a0p + (size_t)16*K2;
  f32x4 acc[2][8] = {};
  f4 Ar[2][8];
  // prologue: prefetch tile 0
  {
    const f4* p0 = (const f4*)a0p;
    const f4* p1 = (const f4*)a1p;
    Ar[0][0] = __builtin_nontemporal_load(p0);
    Ar[0][1] = __builtin_nontemporal_load(p0 + 1);
    Ar[0][2] = __builtin_nontemporal_load(p1);
    Ar[0][3] = __builtin_nontemporal_load(p1 + 1);
    Ar[0][4] = __builtin_nontemporal_load(p0 + 8);   // +32 floats
    Ar[0][5] = __builtin_nontemporal_load(p0 + 9);
    Ar[0][6] = __builtin_nontemporal_load(p1 + 8);
    Ar[0][7] = __builtin_nontemporal_load(p1 + 9);
  }
  #pragma unroll 2
  for (int tile = 0; tile < 64; ++tile){
    int cur = tile & 1;                          // static after unroll-2
    // issue next tile's A-loads first (long-latency HBM stream)
    if (tile < 63){
      const f4* p0 = (const f4*)(a0p + (tile+1)*64);
      const f4* p1 = (const f4*)(a1p + (tile+1)*64);
      Ar[cur^1][0] = __builtin_nontemporal_load(p0);
      Ar[cur^1][1] = __builtin_nontemporal_load(p0 + 1);
      Ar[cur^1][2] = __builtin_nontemporal_load(p1);
      Ar[cur^1][3] = __builtin_nontemporal_load(p1 + 1);
      Ar[cur^1][4] = __builtin_nontemporal_load(p0 + 8);
      Ar[cur^1][5] = __builtin_nontemporal_load(p0 + 9);
      Ar[cur^1][6] = __builtin_nontemporal_load(p1 + 8);
      Ar[cur^1][7] = __builtin_nontemporal_load(p1 + 9);
    }
    // stage B tile (128 o x 64 k), 16B-slot XOR swizzle
    size_t kt = kbase + tile*64;
    #pragma unroll
    for (int pp = 0; pp < 4; ++pp){
      int q = pp*256 + t;
      int o = q >> 3, oct = q & 7;
      uint4 v = *(const uint4*)(BpT + (size_t)o*K2 + kt + oct*8);
      *(uint4*)((char*)Bs + o*128 + ((oct ^ (o & 7)) << 4)) = v;
    }
    __syncthreads();                             // drains staging + prefetch together
    #pragma unroll
    for (int s = 0; s < 2; ++s){
      bf16x8 a0 = cvt8t(Ar[cur][s*4+0], Ar[cur][s*4+1]);
      bf16x8 a1 = cvt8t(Ar[cur][s*4+2], Ar[cur][s*4+3]);
      int khalf = s*4 + lk;
      #pragma unroll
      for (int cf = 0; cf < 8; ++cf){
        int o = cf*16 + lr;
        bf16x8 bfr = *(const bf16x8*)((char*)Bs + o*128 + ((khalf ^ (o & 7)) << 4));
        acc[0][cf] = __builtin_amdgcn_mfma_f32_16x16x32_bf16(a0, bfr, acc[0][cf], 0, 0, 0);
        acc[1][cf] = __builtin_amdgcn_mfma_f32_16x16x32_bf16(a1, bfr, acc[1][cf], 0, 0, 0);
      }
    }
    __syncthreads();
  }
  int orow = rowtile*128 + w*32 + lk*4;
  #pragma unroll
  for (int rf = 0; rf < 2; ++rf){
    #pragma unroll
    for (int cf = 0; cf < 8; ++cf){
      #pragma unroll
      for (int j = 0; j < 4; ++j){
        unsafeAtomicAdd(out + (size_t)(orow + rf*16 + j)*128 + cf*16 + lr, acc[rf][cf][j]);
      }
    }
  }
}

// BatchNorm stats with half-ReLU on read; row-contiguous reads
__global__ __launch_bounds__(256) void colstats(const float* __restrict__ acc,
                                                float* __restrict__ gsum,
                                                float* __restrict__ gsumsq){
  __shared__ float s1[8][128], s2[8][128];
  int t = threadIdx.x;
  int c4 = (t & 31)*4, rsub = t >> 5;
  int rbase = blockIdx.x*32;
  f4 sum = {0,0,0,0}, sq = {0,0,0,0};
  #pragma unroll
  for (int i = 0; i < 4; ++i){
    f4 v = *(const f4*)(acc + (size_t)(rbase + rsub + i*8)*128 + c4);
    if (c4 >= 64){
      v.x=fmaxf(v.x,0.f); v.y=fmaxf(v.y,0.f); v.z=fmaxf(v.z,0.f); v.w=fmaxf(v.w,0.f);
    }
    sum += v; sq += v*v;
  }
  *(f4*)&s1[rsub][c4] = sum;
  *(f4*)&s2[rsub][c4] = sq;
  __syncthreads();
  if (t < 128){
    float a = 0.f, b2 = 0.f;
    #pragma unroll
    for (int r = 0; r < 8; ++r){ a += s1[r][t]; b2 += s2[r][t]; }
    unsafeAtomicAdd(gsum + t, a);
    unsafeAtomicAdd(gsumsq + t, b2);
  }
}

__global__ void bn_final(const float* __restrict__ gsum, const float* __restrict__ gsumsq,
                         const float* __restrict__ gamma, const float* __restrict__ beta,
                         float* __restrict__ scale, float* __restrict__ shift){
  int c = threadIdx.x;
  float mean = gsum[c] * (1.f/8192.f);
  float var  = gsumsq[c] * (1.f/8192.f) - mean*mean;
  float rstd = rsqrtf(var + 1e-5f);
  float sc = rstd * gamma[c];
  scale[c] = sc;
  shift[c] = beta[c] - mean*sc;
}

__global__ __launch_bounds__(256) void bn_apply(float* __restrict__ out,
                                                const float* __restrict__ scale,
                                                const float* __restrict__ shift){
  int i = blockIdx.x*256 + threadIdx.x;
  int j = i & 31;
  f4* o4 = (f4*)out;
  f4 v = o4[i];
  if (j >= 16){
    v.x=fmaxf(v.x,0.f); v.y=fmaxf(v.y,0.f); v.z=fmaxf(v.z,0.f); v.w=fmaxf(v.w,0.f);
  }
  f4 sc = *(const f4*)(scale + j*4);
  f4 sh = *(const f4*)(shift + j*4);
  v.x = fmaf(v.x,sc.x,sh.x); v.y = fmaf(v.y,sc.y,sh.y);
  v.z = fmaf(v.z,sc.z,sh.z); v.w = fmaf(v.w,sc.w,sh.w);
  o4[i] = v;
}

extern "C" void kernel_launch(void* const* d_in, const int* in_sizes, int n_in,
                              void* d_out, int out_size, void* d_ws, size_t ws_size,
                              hipStream_t stream) {
  const float* feat_a = (const float*)d_in[0];
  const float* feat_b = (const float*)d_in[1];
  const float* deg    = (const float*)d_in[2];
  const float* pm_pd  = (const float*)d_in[3];
  const int*   src    = (const int*)d_in[4];
  const int*   dst    = (const int*)d_in[5];
  const float* W_prev = (const float*)d_in[6];
  const float* b_prev = (const float*)d_in[7];
  const float* W_deg  = (const float*)d_in[8];
  const float* b_deg  = (const float*)d_in[9];
  const float* W_r    = (const float*)d_in[10];
  const float* b_r    = (const float*)d_in[11];
  const float* W_fuse = (const float*)d_in[12];
  const float* b_fuse = (const float*)d_in[13];
  const float* gamma  = (const float*)d_in[14];
  const float* beta   = (const float*)d_in[15];
  float* out = (float*)d_out;

  char* w = (char*)d_ws;
  u16*   BpT    = (u16*)  (w + 0);          // 8 MB interleaved B'
  float* z0     = (float*)(w + 8388608);
  float* z1     = (float*)(w + 12582912);
  float* ztmp   = (float*)(w + 16777216);
  float* z2     = (float*)(w + 20971520);
  u16*   WfT    = (u16*)  (w + 25165824);
  int*   hist   = (int*)  (w + 25231360);
  int*   off    = (int*)  (w + 25264128);
  int*   cursor = (int*)  (w + 25296912);
  int*   eidx   = (int*)  (w + 25329680);
  float* gsum   = (float*)(w + 25853968);
  float* gsumsq = gsum + 128;
  float* scale  = (float*)(w + 25854992);
  float* shift  = (float*)(w + 25855504);
  if (ws_size < (size_t)25856016) return;

  hipMemsetAsync(hist, 0, NN*sizeof(int), stream);
  hipMemsetAsync(gsum, 0, 256*sizeof(float), stream);

  wft_k<<<256, 128, 0, stream>>>(W_fuse, WfT);
  prep_bpt<<<MM/32, 128, 0, stream>>>(feat_b, WfT, (u32*)BpT);

  hist_k<<<EE/256, 256, 0, stream>>>(dst, hist);
  scan_k<<<1, 256, 0, stream>>>(hist, off, cursor);
  fill_k<<<EE/256, 256, 0, stream>>>(src, dst, cursor, eidx);

  agg_k<<<NN/8, 256, 0, stream>>>(feat_a, z0, off, eidx);
  agg_k<<<NN/8, 256, 0, stream>>>(z0, z1, off, eidx);
  agg_k<<<NN/8, 256, 0, stream>>>(z1, ztmp, off, eidx);
  agg_k<<<NN/8, 256, 0, stream>>>(ztmp, z2, off, eidx);

  proj_all<<<NN/32, 256, 0, stream>>>(feat_a, deg, z0, z1, z2,
                                      W_prev, W_deg, W_r, b_prev, b_deg, b_r, b_fuse, out);

  fuse_gemm<<<512, 256, 0, stream>>>(pm_pd, BpT, out);

  colstats<<<NN/32, 256, 0, stream>>>(out, gsum, gsumsq);
  bn_final<<<1, 128, 0, stream>>>(gsum, gsumsq, gamma, beta, scale, shift);
  bn_apply<<<NN*128/4/256, 256, 0, stream>>>(out, scale, shift);
}